// Round 2
// baseline (105.938 us; speedup 1.0000x reference)
//
#include <hip/hip_runtime.h>
#include <hip/hip_bf16.h>

#define N_NODES 8192
#define IN_FEAT 128
#define OUT_FEAT 64
#define NEG_SLOPE 0.2f
#define TILES (N_NODES / 16)   // 512 row tiles of 16
#define LOG2E 1.44269504088896340736f

using f32x4  = __attribute__((ext_vector_type(4))) float;
using i32x4  = __attribute__((ext_vector_type(4))) int;
using bf16x8 = __attribute__((ext_vector_type(8))) short;

// float -> bf16 bits, round-to-nearest-even (inputs are positive normals, no NaN)
static __device__ __forceinline__ short f2bf(float f) {
    unsigned int u = __float_as_uint(f);
    unsigned int r = (u + 0x7FFFu + ((u >> 16) & 1u)) >> 16;
    return (short)r;
}

// 2^x via v_exp_f32
static __device__ __forceinline__ float exp2_fast(float x) {
    return __builtin_amdgcn_exp2f(x);
}

// ---------------------------------------------------------------------------
// K1: Wh = x @ W  (fp32 in registers); s1 = (Wh@a1)*log2e, s2 = (Wh@a2)*log2e;
//     Wh stored as bf16 directly in MFMA B-fragment layout:
//     whb[((jb*4+fg)*64 + lane)*8 + e] = bf16(Wh[jb*32 + 8*(lane>>4) + e][fg*16 + (lane&15)])
// One wave per row; 4 waves (4 rows) per block.
// ---------------------------------------------------------------------------
__global__ __launch_bounds__(256) void k_wh(
    const float* __restrict__ x, const float* __restrict__ W,
    const float* __restrict__ a,
    float* __restrict__ s1, float* __restrict__ s2,
    unsigned short* __restrict__ whb)
{
    __shared__ float xs[4][IN_FEAT];
    const int wv   = threadIdx.x >> 6;   // wave in block
    const int lane = threadIdx.x & 63;   // feature index
    const int row  = blockIdx.x * 4 + wv;

    const float2 xv = *(const float2*)(x + (size_t)row * IN_FEAT + lane * 2);
    xs[wv][lane * 2]     = xv.x;
    xs[wv][lane * 2 + 1] = xv.y;
    __syncthreads();

    float acc = 0.f;
    #pragma unroll
    for (int k = 0; k < IN_FEAT; ++k)
        acc = fmaf(xs[wv][k], W[k * OUT_FEAT + lane], acc);

    // s1, s2 (wave reduction), pre-scaled by log2(e) so K4 uses exp2 directly
    float p1 = acc * a[lane];
    float p2 = acc * a[OUT_FEAT + lane];
    #pragma unroll
    for (int off = 32; off; off >>= 1) {
        p1 += __shfl_xor(p1, off);
        p2 += __shfl_xor(p2, off);
    }
    if (lane == 0) {
        s1[row] = p1 * LOG2E;
        s2[row] = p2 * LOG2E;
    }

    // B-fragment pack: row 'row' of Wh is k-index ri = row&31 of block jb = row>>5
    const int jb = row >> 5;
    const int ri = row & 31;
    const int gl = ri >> 3;      // which 16-lane group holds this k
    const int e  = ri & 7;       // element slot within lane
    const int fg = lane >> 4;    // feature group (n-tile of 16)
    const int cl = lane & 15;    // n within tile
    whb[(((size_t)(jb * 4 + fg) * 64) + (gl * 16 + cl)) * 8 + e] = (unsigned short)f2bf(acc);
}

// ---------------------------------------------------------------------------
// K4: main pass.  One wave = 16 output rows x 64 features, over a K-chunk of
// columns.  Weights computed per-lane directly in A-fragment layout:
//   A[m][k]: m = lane&15, k = 8*(lane>>4)+e   (e = 0..7)
// w = adj ? exp2(max(t, 0.2t)) : 1,  t = s1'[i] + s2'[j]  (already *log2e).
// Z accumulated in fp32 alongside.  Partials (no rescale needed!) -> ws.
// ---------------------------------------------------------------------------
__global__ __launch_bounds__(64, 4) void k_attn(
    const int* __restrict__ adj, const float* __restrict__ s1v,
    const float* __restrict__ s2v, const unsigned short* __restrict__ whb,
    float* __restrict__ pnum, float* __restrict__ pz)
{
    const int lane   = threadIdx.x;
    const int tile   = blockIdx.x;
    const int chunk  = blockIdx.y;
    const int nchnk  = gridDim.y;
    const int jc     = N_NODES / nchnk;
    const int ksteps = jc / 32;

    const int cl = lane & 15, g = lane >> 4;
    const int row = tile * 16 + cl;
    const float s1r = s1v[row];
    const size_t arow = (size_t)row * N_NODES;
    const int j00 = chunk * jc;

    f32x4 acc0 = {0.f, 0.f, 0.f, 0.f};
    f32x4 acc1 = acc0, acc2 = acc0, acc3 = acc0;
    float zacc = 0.f;

    // prologue: load step 0
    int jl = j00 + 8 * g;
    int jb = j00 >> 5;
    i32x4 aC0 = *(const i32x4*)(adj + arow + jl);
    i32x4 aC1 = *(const i32x4*)(adj + arow + jl + 4);
    f32x4 sC0 = *(const f32x4*)(s2v + jl);
    f32x4 sC1 = *(const f32x4*)(s2v + jl + 4);
    bf16x8 bC0 = *(const bf16x8*)(whb + ((size_t)(jb * 4 + 0) * 64 + lane) * 8);
    bf16x8 bC1 = *(const bf16x8*)(whb + ((size_t)(jb * 4 + 1) * 64 + lane) * 8);
    bf16x8 bC2 = *(const bf16x8*)(whb + ((size_t)(jb * 4 + 2) * 64 + lane) * 8);
    bf16x8 bC3 = *(const bf16x8*)(whb + ((size_t)(jb * 4 + 3) * 64 + lane) * 8);

    for (int t = 0; t < ksteps; ++t) {
        // prefetch next step (1-deep)
        const int tn  = (t + 1 < ksteps) ? t + 1 : t;
        const int j0n = j00 + tn * 32;
        const int jln = j0n + 8 * g;
        const int jbn = j0n >> 5;
        i32x4 aN0 = *(const i32x4*)(adj + arow + jln);
        i32x4 aN1 = *(const i32x4*)(adj + arow + jln + 4);
        f32x4 sN0 = *(const f32x4*)(s2v + jln);
        f32x4 sN1 = *(const f32x4*)(s2v + jln + 4);
        bf16x8 bN0 = *(const bf16x8*)(whb + ((size_t)(jbn * 4 + 0) * 64 + lane) * 8);
        bf16x8 bN1 = *(const bf16x8*)(whb + ((size_t)(jbn * 4 + 1) * 64 + lane) * 8);
        bf16x8 bN2 = *(const bf16x8*)(whb + ((size_t)(jbn * 4 + 2) * 64 + lane) * 8);
        bf16x8 bN3 = *(const bf16x8*)(whb + ((size_t)(jbn * 4 + 3) * 64 + lane) * 8);

        // weights -> A fragment
        bf16x8 af;
        #pragma unroll
        for (int e = 0; e < 4; ++e) {
            float tv = s1r + sC0[e];
            float el = fmaxf(tv, NEG_SLOPE * tv);
            float wv2 = (aC0[e] > 0) ? exp2_fast(el) : 1.0f;
            zacc += wv2;
            af[e] = f2bf(wv2);
        }
        #pragma unroll
        for (int e = 0; e < 4; ++e) {
            float tv = s1r + sC1[e];
            float el = fmaxf(tv, NEG_SLOPE * tv);
            float wv2 = (aC1[e] > 0) ? exp2_fast(el) : 1.0f;
            zacc += wv2;
            af[4 + e] = f2bf(wv2);
        }

        acc0 = __builtin_amdgcn_mfma_f32_16x16x32_bf16(af, bC0, acc0, 0, 0, 0);
        acc1 = __builtin_amdgcn_mfma_f32_16x16x32_bf16(af, bC1, acc1, 0, 0, 0);
        acc2 = __builtin_amdgcn_mfma_f32_16x16x32_bf16(af, bC2, acc2, 0, 0, 0);
        acc3 = __builtin_amdgcn_mfma_f32_16x16x32_bf16(af, bC3, acc3, 0, 0, 0);

        aC0 = aN0; aC1 = aN1; sC0 = sN0; sC1 = sN1;
        bC0 = bN0; bC1 = bN1; bC2 = bN2; bC3 = bN3;
    }

    // Z: combine the 4 lane-groups holding the same row (l&15)
    float z = zacc + __shfl_xor(zacc, 16);
    z += __shfl_xor(z, 32);

    float* pb = pnum + (((size_t)chunk * TILES + tile) * 64 + lane) * 16;
    *(f32x4*)(pb + 0)  = acc0;
    *(f32x4*)(pb + 4)  = acc1;
    *(f32x4*)(pb + 8)  = acc2;
    *(f32x4*)(pb + 12) = acc3;
    if (lane < 16) pz[(size_t)chunk * N_NODES + tile * 16 + lane] = z;
}

// ---------------------------------------------------------------------------
// K5: sum split-K partials, divide by Z, write out.
// D-fragment layout (HW-verified): col = lane&15, row = 4*(lane>>4) + reg.
// ---------------------------------------------------------------------------
__global__ __launch_bounds__(256) void k_out(
    const float* __restrict__ pnum, const float* __restrict__ pz,
    float* __restrict__ out, int nchunks)
{
    const int idx = blockIdx.x * 256 + threadIdx.x;   // < 8192*64
    const int row = idx >> 6, f = idx & 63;
    const int tile = row >> 4, rit = row & 15;
    const int g = rit >> 2, q = rit & 3;
    const int lane = g * 16 + (f & 15);
    const int fg = f >> 4;

    float num = 0.f, z = 0.f;
    for (int c = 0; c < nchunks; ++c) {
        num += pnum[(((size_t)c * TILES + tile) * 64 + lane) * 16 + fg * 4 + q];
        z   += pz[(size_t)c * N_NODES + tile * 16 + rit];
    }
    out[idx] = num / z;
}

// ---------------------------------------------------------------------------
extern "C" void kernel_launch(void* const* d_in, const int* in_sizes, int n_in,
                              void* d_out, int out_size, void* d_ws, size_t ws_size,
                              hipStream_t stream) {
    const float* x   = (const float*)d_in[0];
    const int*   adj = (const int*)d_in[1];
    const float* W   = (const float*)d_in[2];
    const float* a   = (const float*)d_in[3];
    float* out = (float*)d_out;

    char* ws = (char*)d_ws;
    float* s1 = (float*)(ws);                         // 32 KB
    float* s2 = (float*)(ws + 32 * 1024);             // 32 KB
    unsigned short* whb = (unsigned short*)(ws + 64 * 1024);  // 1 MB
    const size_t fixed = 2u * 1024 * 1024;

    // split-K factor: as many chunks as ws allows (occupancy), up to 8
    int chunks = 8;
    while (chunks > 1) {
        size_t need = fixed + (size_t)chunks * TILES * 64 * 16 * 4
                            + (size_t)chunks * N_NODES * 4;
        if (need <= ws_size) break;
        chunks >>= 1;
    }
    float* pnum = (float*)(ws + fixed);
    float* pz   = (float*)(ws + fixed + (size_t)chunks * TILES * 64 * 16 * 4);

    k_wh  <<<dim3(N_NODES / 4), dim3(256), 0, stream>>>(x, W, a, s1, s2, whb);
    k_attn<<<dim3(TILES, chunks), dim3(64), 0, stream>>>(adj, s1, s2, whb, pnum, pz);
    k_out <<<dim3(N_NODES * OUT_FEAT / 256), dim3(256), 0, stream>>>(pnum, pz, out, chunks);
}

// Round 3
// 105.798 us; speedup vs baseline: 1.0013x; 1.0013x over previous
//
#include <hip/hip_runtime.h>
#include <hip/hip_bf16.h>

#define N_NODES 8192
#define IN_FEAT 128
#define OUT_FEAT 64
#define NEG_SLOPE 0.2f
#define TILES (N_NODES / 16)   // 512 row tiles of 16
#define LOG2E 1.44269504088896340736f

using f32x4  = __attribute__((ext_vector_type(4))) float;
using i32x4  = __attribute__((ext_vector_type(4))) int;
using bf16x8 = __attribute__((ext_vector_type(8))) short;

// float -> bf16 bits, round-to-nearest-even (inputs are positive normals, no NaN)
static __device__ __forceinline__ short f2bf(float f) {
    unsigned int u = __float_as_uint(f);
    unsigned int r = (u + 0x7FFFu + ((u >> 16) & 1u)) >> 16;
    return (short)r;
}

// 2^x via v_exp_f32
static __device__ __forceinline__ float exp2_fast(float x) {
    return __builtin_amdgcn_exp2f(x);
}

// ---------------------------------------------------------------------------
// K1: Wh = x @ W  (fp32 in registers); s1 = (Wh@a1)*log2e, s2 = (Wh@a2)*log2e;
//     Wh stored as bf16 directly in MFMA B-fragment layout:
//     whb[((jb*4+fg)*64 + lane)*8 + e] = bf16(Wh[jb*32 + 8*(lane>>4) + e][fg*16 + (lane&15)])
// One wave per row; 4 waves (4 rows) per block.
// ---------------------------------------------------------------------------
__global__ __launch_bounds__(256) void k_wh(
    const float* __restrict__ x, const float* __restrict__ W,
    const float* __restrict__ a,
    float* __restrict__ s1, float* __restrict__ s2,
    unsigned short* __restrict__ whb)
{
    __shared__ float xs[4][IN_FEAT];
    const int wv   = threadIdx.x >> 6;   // wave in block
    const int lane = threadIdx.x & 63;   // feature index
    const int row  = blockIdx.x * 4 + wv;

    const float2 xv = *(const float2*)(x + (size_t)row * IN_FEAT + lane * 2);
    xs[wv][lane * 2]     = xv.x;
    xs[wv][lane * 2 + 1] = xv.y;
    __syncthreads();

    float acc = 0.f;
    #pragma unroll
    for (int k = 0; k < IN_FEAT; ++k)
        acc = fmaf(xs[wv][k], W[k * OUT_FEAT + lane], acc);

    // s1, s2 (wave reduction), pre-scaled by log2(e) so K4 uses exp2 directly
    float p1 = acc * a[lane];
    float p2 = acc * a[OUT_FEAT + lane];
    #pragma unroll
    for (int off = 32; off; off >>= 1) {
        p1 += __shfl_xor(p1, off);
        p2 += __shfl_xor(p2, off);
    }
    if (lane == 0) {
        s1[row] = p1 * LOG2E;
        s2[row] = p2 * LOG2E;
    }

    // B-fragment pack: row 'row' of Wh is k-index ri = row&31 of block jb = row>>5
    const int jb = row >> 5;
    const int ri = row & 31;
    const int gl = ri >> 3;      // which 16-lane group holds this k
    const int e  = ri & 7;       // element slot within lane
    const int fg = lane >> 4;    // feature group (n-tile of 16)
    const int cl = lane & 15;    // n within tile
    whb[(((size_t)(jb * 4 + fg) * 64) + (gl * 16 + cl)) * 8 + e] = (unsigned short)f2bf(acc);
}

// ---------------------------------------------------------------------------
// K4: main pass.  One wave = 16 output rows x 64 features, over a K-chunk of
// columns.  Weights computed per-lane directly in A-fragment layout:
//   A[m][k]: m = lane&15, k = 8*(lane>>4)+e   (e = 0..7)
// w = adj ? exp2(max(t, 0.2t)) : 1,  t = s1'[i] + s2'[j]  (already *log2e).
// Z accumulated in fp32 alongside.  Partials (no rescale needed!) -> ws.
// ---------------------------------------------------------------------------
__global__ __launch_bounds__(64, 4) void k_attn(
    const int* __restrict__ adj, const float* __restrict__ s1v,
    const float* __restrict__ s2v, const unsigned short* __restrict__ whb,
    float* __restrict__ pnum, float* __restrict__ pz)
{
    const int lane   = threadIdx.x;
    const int tile   = blockIdx.x;
    const int chunk  = blockIdx.y;
    const int nchnk  = gridDim.y;
    const int jc     = N_NODES / nchnk;
    const int ksteps = jc / 32;

    const int cl = lane & 15, g = lane >> 4;
    const int row = tile * 16 + cl;
    const float s1r = s1v[row];
    const size_t arow = (size_t)row * N_NODES;
    const int j00 = chunk * jc;

    f32x4 acc0 = {0.f, 0.f, 0.f, 0.f};
    f32x4 acc1 = acc0, acc2 = acc0, acc3 = acc0;
    float zacc = 0.f;

    // prologue: load step 0
    int jl = j00 + 8 * g;
    int jb = j00 >> 5;
    i32x4 aC0 = *(const i32x4*)(adj + arow + jl);
    i32x4 aC1 = *(const i32x4*)(adj + arow + jl + 4);
    f32x4 sC0 = *(const f32x4*)(s2v + jl);
    f32x4 sC1 = *(const f32x4*)(s2v + jl + 4);
    bf16x8 bC0 = *(const bf16x8*)(whb + ((size_t)(jb * 4 + 0) * 64 + lane) * 8);
    bf16x8 bC1 = *(const bf16x8*)(whb + ((size_t)(jb * 4 + 1) * 64 + lane) * 8);
    bf16x8 bC2 = *(const bf16x8*)(whb + ((size_t)(jb * 4 + 2) * 64 + lane) * 8);
    bf16x8 bC3 = *(const bf16x8*)(whb + ((size_t)(jb * 4 + 3) * 64 + lane) * 8);

    for (int t = 0; t < ksteps; ++t) {
        // prefetch next step (1-deep)
        const int tn  = (t + 1 < ksteps) ? t + 1 : t;
        const int j0n = j00 + tn * 32;
        const int jln = j0n + 8 * g;
        const int jbn = j0n >> 5;
        i32x4 aN0 = *(const i32x4*)(adj + arow + jln);
        i32x4 aN1 = *(const i32x4*)(adj + arow + jln + 4);
        f32x4 sN0 = *(const f32x4*)(s2v + jln);
        f32x4 sN1 = *(const f32x4*)(s2v + jln + 4);
        bf16x8 bN0 = *(const bf16x8*)(whb + ((size_t)(jbn * 4 + 0) * 64 + lane) * 8);
        bf16x8 bN1 = *(const bf16x8*)(whb + ((size_t)(jbn * 4 + 1) * 64 + lane) * 8);
        bf16x8 bN2 = *(const bf16x8*)(whb + ((size_t)(jbn * 4 + 2) * 64 + lane) * 8);
        bf16x8 bN3 = *(const bf16x8*)(whb + ((size_t)(jbn * 4 + 3) * 64 + lane) * 8);

        // weights -> A fragment
        bf16x8 af;
        #pragma unroll
        for (int e = 0; e < 4; ++e) {
            float tv = s1r + sC0[e];
            float el = fmaxf(tv, NEG_SLOPE * tv);
            float wv2 = (aC0[e] > 0) ? exp2_fast(el) : 1.0f;
            zacc += wv2;
            af[e] = f2bf(wv2);
        }
        #pragma unroll
        for (int e = 0; e < 4; ++e) {
            float tv = s1r + sC1[e];
            float el = fmaxf(tv, NEG_SLOPE * tv);
            float wv2 = (aC1[e] > 0) ? exp2_fast(el) : 1.0f;
            zacc += wv2;
            af[4 + e] = f2bf(wv2);
        }

        acc0 = __builtin_amdgcn_mfma_f32_16x16x32_bf16(af, bC0, acc0, 0, 0, 0);
        acc1 = __builtin_amdgcn_mfma_f32_16x16x32_bf16(af, bC1, acc1, 0, 0, 0);
        acc2 = __builtin_amdgcn_mfma_f32_16x16x32_bf16(af, bC2, acc2, 0, 0, 0);
        acc3 = __builtin_amdgcn_mfma_f32_16x16x32_bf16(af, bC3, acc3, 0, 0, 0);

        aC0 = aN0; aC1 = aN1; sC0 = sN0; sC1 = sN1;
        bC0 = bN0; bC1 = bN1; bC2 = bN2; bC3 = bN3;
    }

    // Z: combine the 4 lane-groups holding the same row (l&15)
    float z = zacc + __shfl_xor(zacc, 16);
    z += __shfl_xor(z, 32);

    float* pb = pnum + (((size_t)chunk * TILES + tile) * 64 + lane) * 16;
    *(f32x4*)(pb + 0)  = acc0;
    *(f32x4*)(pb + 4)  = acc1;
    *(f32x4*)(pb + 8)  = acc2;
    *(f32x4*)(pb + 12) = acc3;
    if (lane < 16) pz[(size_t)chunk * N_NODES + tile * 16 + lane] = z;
}

// ---------------------------------------------------------------------------
// K5: sum split-K partials, divide by Z, write out.
// D-fragment layout (HW-verified): col = lane&15, row = 4*(lane>>4) + reg.
// ---------------------------------------------------------------------------
__global__ __launch_bounds__(256) void k_out(
    const float* __restrict__ pnum, const float* __restrict__ pz,
    float* __restrict__ out, int nchunks)
{
    const int idx = blockIdx.x * 256 + threadIdx.x;   // < 8192*64
    const int row = idx >> 6, f = idx & 63;
    const int tile = row >> 4, rit = row & 15;
    const int g = rit >> 2, q = rit & 3;
    const int lane = g * 16 + (f & 15);
    const int fg = f >> 4;

    float num = 0.f, z = 0.f;
    for (int c = 0; c < nchunks; ++c) {
        num += pnum[(((size_t)c * TILES + tile) * 64 + lane) * 16 + fg * 4 + q];
        z   += pz[(size_t)c * N_NODES + tile * 16 + rit];
    }
    out[idx] = num / z;
}

// ---------------------------------------------------------------------------
extern "C" void kernel_launch(void* const* d_in, const int* in_sizes, int n_in,
                              void* d_out, int out_size, void* d_ws, size_t ws_size,
                              hipStream_t stream) {
    const float* x   = (const float*)d_in[0];
    const int*   adj = (const int*)d_in[1];
    const float* W   = (const float*)d_in[2];
    const float* a   = (const float*)d_in[3];
    float* out = (float*)d_out;

    char* ws = (char*)d_ws;
    float* s1 = (float*)(ws);                         // 32 KB
    float* s2 = (float*)(ws + 32 * 1024);             // 32 KB
    unsigned short* whb = (unsigned short*)(ws + 64 * 1024);  // 1 MB
    const size_t fixed = 2u * 1024 * 1024;

    // split-K factor: as many chunks as ws allows (occupancy), up to 8
    int chunks = 8;
    while (chunks > 1) {
        size_t need = fixed + (size_t)chunks * TILES * 64 * 16 * 4
                            + (size_t)chunks * N_NODES * 4;
        if (need <= ws_size) break;
        chunks >>= 1;
    }
    float* pnum = (float*)(ws + fixed);
    float* pz   = (float*)(ws + fixed + (size_t)chunks * TILES * 64 * 16 * 4);

    k_wh  <<<dim3(N_NODES / 4), dim3(256), 0, stream>>>(x, W, a, s1, s2, whb);
    k_attn<<<dim3(TILES, chunks), dim3(64), 0, stream>>>(adj, s1, s2, whb, pnum, pz);
    k_out <<<dim3(N_NODES * OUT_FEAT / 256), dim3(256), 0, stream>>>(pnum, pz, out, chunks);
}